// Round 1
// baseline (8405.029 us; speedup 1.0000x reference)
//
#include <hip/hip_runtime.h>

// ---------------------------------------------------------------------------
// ComNet: R=16 runs x T=512 steps x 32 agents, sequential agent scan.
// Decomposition:
//   k0: transpose W1[:, :93] -> w1T (coalesced access in k1)
//   k1: pre1[rti][h] = b1[h] + xs(93) . W1xs  (parallel, bulk of FLOPs)
//   k2: sequential kernel, 16 blocks x 64 thr: per step only the comm-dependent
//       part. O(1)/step comm-dot via FB/Q/S bookkeeping. Stores h2 over pre1.
//   k3: ctrl[rti][0:2] = W3[0:2] @ h2 + b3[0:2]  (parallel epilogue)
// Fallback (ws too small): fully fused sequential kernel, no workspace.
// ---------------------------------------------------------------------------

#define R_RUNS 16
#define T_STEPS 512
#define NA 32
#define HID 64
#define XS 93                       // (NA-1)*3
#define DIN 124
#define STEPS_PER_RUN (T_STEPS * NA)        // 16384
#define RTI_TOT (R_RUNS * STEPS_PER_RUN)    // 262144

#define PRE1_OFF 65536
#define WS_NEEDED ((size_t)PRE1_OFF + (size_t)RTI_TOT * HID * 4 + 512)

__device__ __forceinline__ float fast_tanh(float x) {
  float xc = fminf(fmaxf(x, -15.f), 15.f);
  float e = __expf(2.f * xc);
  return (e - 1.f) * __builtin_amdgcn_rcpf(e + 1.f);
}

// wave64 sum -> broadcast (value returned uniform to all lanes)
#define DPP_ADD(x, ctrl, rmask) \
  (x) += __int_as_float(__builtin_amdgcn_update_dpp(0, __float_as_int(x), (ctrl), (rmask), 0xf, true))

__device__ __forceinline__ float wave64_sum_bcast(float x) {
  DPP_ADD(x, 0x111, 0xf);  // row_shr:1
  DPP_ADD(x, 0x112, 0xf);  // row_shr:2
  DPP_ADD(x, 0x114, 0xf);  // row_shr:4
  DPP_ADD(x, 0x118, 0xf);  // row_shr:8
  DPP_ADD(x, 0x142, 0xa);  // row_bcast:15 -> rows 1,3
  DPP_ADD(x, 0x143, 0xc);  // row_bcast:31 -> rows 2,3
  return __int_as_float(__builtin_amdgcn_readlane(__float_as_int(x), 63));
}

// ---------------- k0: transpose W1 xs-part ----------------
__global__ void transpose_w1(const float* __restrict__ w1, float* __restrict__ w1T) {
  int idx = blockIdx.x * blockDim.x + threadIdx.x;  // idx = k*64 + h
  if (idx < XS * HID) {
    int k = idx / HID, h = idx % HID;
    w1T[idx] = w1[h * DIN + k];
  }
}

// ---------------- k1: pre1 = b1 + xs @ W1xs^T ----------------
__global__ __launch_bounds__(256) void pre1_kernel(
    const float* __restrict__ runs, const float* __restrict__ w1T,
    const float* __restrict__ b1, float* __restrict__ pre1) {
  const int wid = (blockIdx.x * 256 + threadIdx.x) >> 6;  // rti, one wave each
  const int lane = threadIdx.x & 63;
  const float* xs = runs + (size_t)wid * XS;
  float a0 = b1[lane], a1 = 0.f, a2 = 0.f;
#pragma unroll 4
  for (int k = 0; k < 31; ++k) {
    a0 = fmaf(xs[3 * k],     w1T[(3 * k) * HID + lane],     a0);
    a1 = fmaf(xs[3 * k + 1], w1T[(3 * k + 1) * HID + lane], a1);
    a2 = fmaf(xs[3 * k + 2], w1T[(3 * k + 2) * HID + lane], a2);
  }
  pre1[(size_t)wid * HID + lane] = (a0 + a1) + a2;
}

// ---------------- k2: sequential core ----------------
// comm-weight bookkeeping:
//   A[h][j] = w1[h][93+j] (j=0..30, A[h][31]=0) : weight of comm[j] when j<i
//   B[h][j] = w1[h][92+j] (j=1..31, B[h][0]=0) : weight of comm[j] when j>i
//   h1pre = pre1 + FB + Q - S, FB = sum_j B*comm_old (refreshed each t),
//   S += B[h][i]*old_i (start of step), Q += A[h][i]*c_new (end of step)
__global__ __launch_bounds__(64, 1) void seq_kernel(
    const float* __restrict__ w1, const float* __restrict__ w2,
    const float* __restrict__ b2, const float* __restrict__ w3,
    const float* __restrict__ b3, const float* __restrict__ comm_init,
    float* __restrict__ pre1) {
  const int r = blockIdx.x;
  const int h = threadIdx.x;
  const int hb = h * 33;

  __shared__ float Asl[HID * 33];
  __shared__ float Bsl[HID * 33];
  __shared__ float commL[NA];
  __shared__ __align__(16) float h1s[HID];

  for (int j = 0; j < 31; ++j) Asl[hb + j] = w1[h * DIN + 93 + j];
  Asl[hb + 31] = 0.f;
  Bsl[hb] = 0.f;
  for (int j = 1; j < 32; ++j) Bsl[hb + j] = w1[h * DIN + 92 + j];

  float w2r[HID];
#pragma unroll
  for (int k = 0; k < HID; ++k) w2r[k] = w2[h * HID + k];
  const float b2h = b2[h];
  const float w32h = w3[2 * HID + h];
  const float b32 = b3[2];
  if (h < NA) commL[h] = comm_init[r * NA + h];
  __syncthreads();

  float* p = pre1 + (size_t)r * STEPS_PER_RUN * HID + h;
  float p_cur = p[0];    // prefetch pipeline depth 2
  float p_n1 = p[64];

  for (int t = 0; t < T_STEPS; ++t) {
    float FB = 0.f;
#pragma unroll
    for (int j = 0; j < NA; ++j) FB = fmaf(Bsl[hb + j], commL[j], FB);
    float Q = 0.f, S = 0.f;
    for (int i = 0; i < NA; ++i) {
      float p_n2 = p[128];            // prefetch 2 steps ahead (512B ws slack)
      float old_i = commL[i];
      S = fmaf(Bsl[hb + i], old_i, S);
      float h1 = fast_tanh(p_cur + FB + Q - S);
      h1s[h] = h1;
      __syncthreads();
      float a0 = b2h, a1 = 0.f, a2 = 0.f, a3 = 0.f;
      const float4* hv4 = (const float4*)h1s;
#pragma unroll
      for (int k4 = 0; k4 < 16; ++k4) {
        float4 hv = hv4[k4];
        a0 = fmaf(w2r[4 * k4 + 0], hv.x, a0);
        a1 = fmaf(w2r[4 * k4 + 1], hv.y, a1);
        a2 = fmaf(w2r[4 * k4 + 2], hv.z, a2);
        a3 = fmaf(w2r[4 * k4 + 3], hv.w, a3);
      }
      float h2 = fast_tanh((a0 + a1) + (a2 + a3));
      p[0] = h2;                       // overwrite consumed pre1 slot with h2
      float c_new = wave64_sum_bcast(w32h * h2) + b32;
      Q = fmaf(Asl[hb + i], c_new, Q);
      if (h == i) commL[h] = c_new;
      __syncthreads();
      p_cur = p_n1; p_n1 = p_n2; p += HID;
    }
  }
}

// ---------------- k3: ctrl epilogue ----------------
__global__ __launch_bounds__(256) void ctrl_kernel(
    const float* __restrict__ h2buf, const float* __restrict__ w3,
    const float* __restrict__ b3, float* __restrict__ out) {
  const int wid = (blockIdx.x * 256 + threadIdx.x) >> 6;
  const int lane = threadIdx.x & 63;
  float v = h2buf[(size_t)wid * HID + lane];
  float s0 = wave64_sum_bcast(w3[lane] * v) + b3[0];
  float s1 = wave64_sum_bcast(w3[HID + lane] * v) + b3[1];
  if (lane == 0) *(float2*)(out + (size_t)wid * 2) = make_float2(s0, s1);
}

// ---------------- fallback: fully fused, zero workspace ----------------
__global__ __launch_bounds__(64, 1) void seq_fused(
    const float* __restrict__ runs, const float* __restrict__ comm_init,
    const float* __restrict__ w1, const float* __restrict__ b1,
    const float* __restrict__ w2, const float* __restrict__ b2,
    const float* __restrict__ w3, const float* __restrict__ b3,
    float* __restrict__ out) {
  const int r = blockIdx.x;
  const int h = threadIdx.x;
  const int hb = h * 33;

  __shared__ float Asl[HID * 33];
  __shared__ float Bsl[HID * 33];
  __shared__ float commL[NA];
  __shared__ __align__(16) float h1s[HID];
  __shared__ float w1xs[XS * HID];
  __shared__ __align__(16) float xsl[96];

  for (int j = 0; j < 31; ++j) Asl[hb + j] = w1[h * DIN + 93 + j];
  Asl[hb + 31] = 0.f;
  Bsl[hb] = 0.f;
  for (int j = 1; j < 32; ++j) Bsl[hb + j] = w1[h * DIN + 92 + j];
  for (int k = 0; k < XS; ++k) w1xs[k * HID + h] = w1[h * DIN + k];

  float w2r[HID];
#pragma unroll
  for (int k = 0; k < HID; ++k) w2r[k] = w2[h * HID + k];
  const float b1h = b1[h];
  const float b2h = b2[h];
  const float w30h = w3[h], w31h = w3[HID + h], w32h = w3[2 * HID + h];
  const float b30 = b3[0], b31 = b3[1], b32 = b3[2];
  if (h < NA) commL[h] = comm_init[r * NA + h];

  const float* xbase = runs + (size_t)r * STEPS_PER_RUN * XS;
  float xa = xbase[h];
  float xb = (h < XS - 64) ? xbase[64 + h] : 0.f;
  float* outp = out + (size_t)r * STEPS_PER_RUN * 2;
  __syncthreads();

  int s = 0;
  for (int t = 0; t < T_STEPS; ++t) {
    float FB = 0.f;
#pragma unroll
    for (int j = 0; j < NA; ++j) FB = fmaf(Bsl[hb + j], commL[j], FB);
    float Q = 0.f, S = 0.f;
    for (int i = 0; i < NA; ++i, ++s) {
      int sn = s + 1; if (sn > STEPS_PER_RUN - 1) sn = STEPS_PER_RUN - 1;
      const float* xn = xbase + (size_t)sn * XS;
      xsl[h] = xa;
      if (h < XS - 64) xsl[64 + h] = xb;
      __syncthreads();
      float xa_n = xn[h];                              // prefetch next step xs
      float xb_n = (h < XS - 64) ? xn[64 + h] : 0.f;
      float a0 = b1h, a1 = 0.f, a2 = 0.f;
#pragma unroll 4
      for (int k = 0; k < 31; ++k) {
        a0 = fmaf(xsl[3 * k],     w1xs[(3 * k) * HID + h],     a0);
        a1 = fmaf(xsl[3 * k + 1], w1xs[(3 * k + 1) * HID + h], a1);
        a2 = fmaf(xsl[3 * k + 2], w1xs[(3 * k + 2) * HID + h], a2);
      }
      float old_i = commL[i];
      S = fmaf(Bsl[hb + i], old_i, S);
      float h1 = fast_tanh(((a0 + a1) + a2) + FB + Q - S);
      h1s[h] = h1;
      __syncthreads();
      float c0 = b2h, c1 = 0.f, c2 = 0.f, c3 = 0.f;
      const float4* hv4 = (const float4*)h1s;
#pragma unroll
      for (int k4 = 0; k4 < 16; ++k4) {
        float4 hv = hv4[k4];
        c0 = fmaf(w2r[4 * k4 + 0], hv.x, c0);
        c1 = fmaf(w2r[4 * k4 + 1], hv.y, c1);
        c2 = fmaf(w2r[4 * k4 + 2], hv.z, c2);
        c3 = fmaf(w2r[4 * k4 + 3], hv.w, c3);
      }
      float h2 = fast_tanh((c0 + c1) + (c2 + c3));
      float o0 = wave64_sum_bcast(w30h * h2) + b30;
      float o1 = wave64_sum_bcast(w31h * h2) + b31;
      float c_new = wave64_sum_bcast(w32h * h2) + b32;
      if (h == 0) *(float2*)(outp + (size_t)s * 2) = make_float2(o0, o1);
      Q = fmaf(Asl[hb + i], c_new, Q);
      if (h == i) commL[h] = c_new;
      __syncthreads();
      xa = xa_n; xb = xb_n;
    }
  }
}

extern "C" void kernel_launch(void* const* d_in, const int* in_sizes, int n_in,
                              void* d_out, int out_size, void* d_ws, size_t ws_size,
                              hipStream_t stream) {
  const float* runs = (const float*)d_in[0];
  const float* comm_init = (const float*)d_in[1];
  const float* w1 = (const float*)d_in[2];
  const float* b1 = (const float*)d_in[3];
  const float* w2 = (const float*)d_in[4];
  const float* b2 = (const float*)d_in[5];
  const float* w3 = (const float*)d_in[6];
  const float* b3 = (const float*)d_in[7];
  float* out = (float*)d_out;

  if (ws_size >= WS_NEEDED) {
    float* w1T = (float*)d_ws;
    float* pre1 = (float*)((char*)d_ws + PRE1_OFF);
    hipLaunchKernelGGL(transpose_w1, dim3((XS * HID + 255) / 256), dim3(256), 0, stream,
                       w1, w1T);
    hipLaunchKernelGGL(pre1_kernel, dim3(RTI_TOT / 4), dim3(256), 0, stream,
                       runs, w1T, b1, pre1);
    hipLaunchKernelGGL(seq_kernel, dim3(R_RUNS), dim3(64), 0, stream,
                       w1, w2, b2, w3, b3, comm_init, pre1);
    hipLaunchKernelGGL(ctrl_kernel, dim3(RTI_TOT / 4), dim3(256), 0, stream,
                       pre1, w3, b3, out);
  } else {
    hipLaunchKernelGGL(seq_fused, dim3(R_RUNS), dim3(64), 0, stream,
                       runs, comm_init, w1, b1, w2, b2, w3, b3, out);
  }
}